// Round 1
// baseline (630.361 us; speedup 1.0000x reference)
//
#include <hip/hip_runtime.h>
#include <math.h>

#define NZ 40
#define NY 256
#define NX 256
#define NUX 257                 // Nx+1
#define NYX (NY*NX)             // 65536
#define KU (NY*NUX)             // per-k stride of U: 65792
#define KV ((NY+1)*NX)          // per-k stride of V: 65792
#define NUT (NZ*KU)             // 2631680
#define NVT (NZ*KV)             // 2631680
#define NCT (NZ*NYX)            // 2621440
#define NWT ((NZ-1)*NYX)        // 2555904

__device__ __forceinline__ int ICc(int k,int j,int i){ return (k*NY+j)*NX+i; }
__device__ __forceinline__ int IU (int k,int j,int i){ return (k*NY+j)*NUX+i; }
__device__ __forceinline__ int IV (int k,int j,int i){ return (k*(NY+1)+j)*NX+i; }

// Column sweep: alpha, theta, p (Nz levels) and w, Omega (Nz-1 levels)
__global__ __launch_bounds__(256) void diag_col(
    const float* __restrict__ Ws, const float* __restrict__ Ts,
    const float* __restrict__ Ms, const float* __restrict__ Ps,
    float* __restrict__ wd, float* __restrict__ thd, float* __restrict__ ald,
    float* __restrict__ pd, float* __restrict__ Omd,
    const float* __restrict__ dzp, const float* __restrict__ PREFp,
    const float* __restrict__ Rdp, const float* __restrict__ gp)
{
  int t = blockIdx.x*blockDim.x+threadIdx.x;
  if (t >= NYX) return;
  const float rdz  = 1.f/(*dzp);
  const float PREF = *PREFp, Rd = *Rdp, g = *gp;
  const float invP = 1.f/PREF;
  float alm=0.f, mum=0.f, phim=0.f;
  for (int k=0;k<NZ;k++){
    int c = k*NYX+t;
    float mu   = Ms[c];
    float phik = (k<NZ-1)? Ps[c] : 0.f;              // pad_z: zero above top
    float al   = -((phik-phim)*rdz)/mu;
    float th   = Ts[c]/mu;
    float pp   = PREF*powf(Rd*th*invP/al, 1.4f);
    ald[c]=al; thd[c]=th; pd[c]=pp;
    if (k>0){
      int cm = c-NYX;
      float muz = 0.5f*(mum+mu), alz = 0.5f*(alm+al);
      float Wv = Ws[cm];
      wd[cm]  = Wv/muz;
      Omd[cm] = -Wv*g/(muz*alz);                     // omega*bar_z(Mu)
    }
    alm=al; mum=mu; phim=phik;
  }
}

// u = U / bar_x(pad_x(Mu));  v = V / bar_y(pad_y(Mu))
__global__ __launch_bounds__(256) void diag_uv(
    const float* __restrict__ Us, const float* __restrict__ Vs,
    const float* __restrict__ Ms, float* __restrict__ ud, float* __restrict__ vd)
{
  int idx = blockIdx.x*blockDim.x+threadIdx.x;
  if (idx < NUT) {
    int k = idx / KU; int r = idx % KU; int j = r / NUX; int i = r % NUX;
    int ii = i % NX, im = (i+NX-1)%NX;
    int b = (k*NY+j)*NX;
    ud[idx] = Us[idx] / (0.5f*(Ms[b+im]+Ms[b+ii]));
  } else if (idx < NUT+NVT) {
    int x = idx-NUT;
    int k = x / KV; int r = x % KV; int j = r / NX; int i = r % NX;
    int jj = j % NY, jm = (j+NY-1)%NY;
    vd[x] = Vs[x] / (0.5f*(Ms[(k*NY+jm)*NX+i]+Ms[(k*NY+jj)*NX+i]));
  }
}

// Fused RHS + stage update. Grid: (ceil(257*257/256), NZ). out = base + c*R(state)
__global__ __launch_bounds__(256) void rhs_update(
    const float* __restrict__ Us, const float* __restrict__ Vs, const float* __restrict__ Ws,
    const float* __restrict__ Ts, const float* __restrict__ Ms, const float* __restrict__ Ps,
    const float* __restrict__ ud, const float* __restrict__ vd, const float* __restrict__ wd,
    const float* __restrict__ thd, const float* __restrict__ ald, const float* __restrict__ pd,
    const float* __restrict__ Omd,
    const float* __restrict__ Ub, const float* __restrict__ Vb, const float* __restrict__ Wb,
    const float* __restrict__ Tb, const float* __restrict__ Mb, const float* __restrict__ Pb,
    float* __restrict__ Uo, float* __restrict__ Vo, float* __restrict__ Wo,
    float* __restrict__ To, float* __restrict__ Mo, float* __restrict__ Po,
    const float* __restrict__ dxp, const float* __restrict__ dyp, const float* __restrict__ dzp,
    const float* __restrict__ dtp, const float* __restrict__ gp, float cmul)
{
  int t = blockIdx.x*blockDim.x+threadIdx.x;
  if (t >= NUX*NUX) return;
  const int k = blockIdx.y;
  const int i = t % NUX;     // 0..256
  const int j = t / NUX;     // 0..256
  const float rdx = 1.f/(*dxp), rdy = 1.f/(*dyp), rdz = 1.f/(*dzp);
  const float g = *gp;
  const float c = (*dtp)*cmul;

  const int ii  = i % NX;
  const int im1 = (i+NX-1) % NX;
  const int jj  = j % NY;
  const int jm1 = (j+NY-1) % NY;

  // ================= R_U : j<NY, i in [0,NX] =================
  if (j < NY) {
    const int iW = (i+NX) % NUX;   // (i-1) mod 257
    const int iE = (i+1) % NUX;
    const int bU = k*KU + j*NUX;
    float Uim = Us[bU+iW], Ui0 = Us[bU+i], Uip = Us[bU+iE];
    float uim = ud[bU+iW], ui0 = ud[bU+i], uip = ud[bU+iE];
    float t1 = -(0.25f*(Ui0+Uip)*(ui0+uip) - 0.25f*(Uim+Ui0)*(uim+ui0))*rdx;

    int jp = j+1, jpm = jp % NY;
    float Vx0 = 0.5f*(Vs[IV(k,j ,im1)] + Vs[IV(k,j ,ii)]);
    float uy0 = 0.5f*(ud[IU(k,jm1,i)] + ud[IU(k,j ,i)]);
    float Vx1 = 0.5f*(Vs[IV(k,jp,im1)] + Vs[IV(k,jp,ii)]);
    float uy1 = 0.5f*(ud[IU(k,j ,i)] + ud[IU(k,jpm,i)]);
    float t2 = -(Vx1*uy1 - Vx0*uy0)*rdy;

    float Omx0 = (k==0)   ? 0.f : 0.5f*(Omd[ICc(k-1,j,im1)]+Omd[ICc(k-1,j,ii)]);
    float uz0  = (k==0)   ? 0.5f*ud[IU(0,j,i)] : 0.5f*(ud[IU(k-1,j,i)]+ud[IU(k,j,i)]);
    float Omx1 = (k+1==NZ)? 0.f : 0.5f*(Omd[ICc(k,j,im1)]+Omd[ICc(k,j,ii)]);
    float uz1  = (k+1==NZ)? 0.5f*ud[IU(NZ-1,j,i)] : 0.5f*(ud[IU(k,j,i)]+ud[IU(k+1,j,i)]);
    float t3 = -(Omx1*uz1 - Omx0*uz0)*rdz;

    float Mux = 0.5f*(Ms[ICc(k,j,im1)]+Ms[ICc(k,j,ii)]);
    float alx = 0.5f*(ald[ICc(k,j,im1)]+ald[ICc(k,j,ii)]);
    float pt1 = -Mux*alx*(pd[ICc(k,j,ii)]-pd[ICc(k,j,im1)])*rdx;

    auto pzf = [&](int m, int x)->float {
      if (m==0)  return 0.5f*pd[ICc(0,j,x)];
      if (m==NZ) return 0.5f*pd[ICc(NZ-1,j,x)];
      return 0.5f*(pd[ICc(m-1,j,x)]+pd[ICc(m,j,x)]);
    };
    float A = (0.5f*(pzf(k+1,im1)+pzf(k+1,ii)) - 0.5f*(pzf(k,im1)+pzf(k,ii)))*rdz;
    auto Phzf = [&](int x)->float {
      if (k==0)    return 0.5f*Ps[ICc(0,j,x)];
      if (k==NZ-1) return 0.5f*Ps[ICc(NZ-2,j,x)];
      return 0.5f*(Ps[ICc(k-1,j,x)]+Ps[ICc(k,j,x)]);
    };
    float B = (Phzf(ii)-Phzf(im1))*rdx;
    float pt2 = -A*B;

    Uo[bU+i] = Ub[bU+i] + c*(t1+t2+t3+pt1+pt2);
  }

  // ================= R_V : i<NX, j in [0,NY] =================
  if (i < NX) {
    const int jN = (j+NY) % NUX;   // (j-1) mod 257 on V's y-grid
    const int jS = (j+1) % NUX;
    float Vjm = Vs[IV(k,jN,i)], Vj0 = Vs[IV(k,j,i)], Vjp = Vs[IV(k,jS,i)];
    float vjm = vd[IV(k,jN,i)], vj0 = vd[IV(k,j,i)], vjp = vd[IV(k,jS,i)];
    float t2 = -(0.25f*(Vj0+Vjp)*(vj0+vjp) - 0.25f*(Vjm+Vj0)*(vjm+vj0))*rdy;

    int ip = i+1, ipm = ip % NX;
    float Uy0 = 0.5f*(Us[IU(k,jm1,i )] + Us[IU(k,jj,i )]);
    float vx0 = 0.5f*(vd[IV(k,j,im1)] + vd[IV(k,j,i)]);
    float Uy1 = 0.5f*(Us[IU(k,jm1,ip)] + Us[IU(k,jj,ip)]);
    float vx1 = 0.5f*(vd[IV(k,j,i)] + vd[IV(k,j,ipm)]);
    float t1 = -(Uy1*vx1 - Uy0*vx0)*rdx;

    float Omy0 = (k==0)   ? 0.f : 0.5f*(Omd[ICc(k-1,jm1,i)]+Omd[ICc(k-1,jj,i)]);
    float vz0  = (k==0)   ? 0.5f*vd[IV(0,j,i)] : 0.5f*(vd[IV(k-1,j,i)]+vd[IV(k,j,i)]);
    float Omy1 = (k+1==NZ)? 0.f : 0.5f*(Omd[ICc(k,jm1,i)]+Omd[ICc(k,jj,i)]);
    float vz1  = (k+1==NZ)? 0.5f*vd[IV(NZ-1,j,i)] : 0.5f*(vd[IV(k,j,i)]+vd[IV(k+1,j,i)]);
    float t3 = -(Omy1*vz1 - Omy0*vz0)*rdz;

    float Muy = 0.5f*(Ms[ICc(k,jm1,i)]+Ms[ICc(k,jj,i)]);
    float aly = 0.5f*(ald[ICc(k,jm1,i)]+ald[ICc(k,jj,i)]);
    float pt1 = -Muy*aly*(pd[ICc(k,jj,i)]-pd[ICc(k,jm1,i)])*rdy;

    auto pzfy = [&](int m, int y)->float {
      if (m==0)  return 0.5f*pd[ICc(0,y,i)];
      if (m==NZ) return 0.5f*pd[ICc(NZ-1,y,i)];
      return 0.5f*(pd[ICc(m-1,y,i)]+pd[ICc(m,y,i)]);
    };
    float A = (0.5f*(pzfy(k+1,jm1)+pzfy(k+1,jj)) - 0.5f*(pzfy(k,jm1)+pzfy(k,jj)))*rdz;
    auto Phzfy = [&](int y)->float {
      if (k==0)    return 0.5f*Ps[ICc(0,y,i)];
      if (k==NZ-1) return 0.5f*Ps[ICc(NZ-2,y,i)];
      return 0.5f*(Ps[ICc(k-1,y,i)]+Ps[ICc(k,y,i)]);
    };
    float B = (Phzfy(jj)-Phzfy(jm1))*rdy;
    float pt2 = -A*B;

    int o = IV(k,j,i);
    Vo[o] = Vb[o] + c*(t1+t2+t3+pt1+pt2);
  }

  // ================= center fields : i<NX, j<NY =================
  if (i < NX && j < NY) {
    const int cc = ICc(k,j,i);
    const int ip1 = (i+1)%NX, jp1 = (j+1)%NY;

    // ---- R_Theta ----
    float thx0 = 0.5f*(thd[ICc(k,j,im1)]+thd[cc]);
    float thx1 = 0.5f*(thd[cc]+thd[ICc(k,j,ip1)]);
    float s1 = -(Us[IU(k,j,i+1)]*thx1 - Us[IU(k,j,i)]*thx0)*rdx;
    float thy0 = 0.5f*(thd[ICc(k,jm1,i)]+thd[cc]);
    float thy1 = 0.5f*(thd[cc]+thd[ICc(k,jp1,i)]);
    float s2 = -(Vs[IV(k,j+1,i)]*thy1 - Vs[IV(k,j,i)]*thy0)*rdy;
    float Om0 = (k==0)    ? 0.f : Omd[ICc(k-1,j,i)];
    float Om1 = (k+1==NZ) ? 0.f : Omd[cc];
    float thz0 = (k==0)    ? 0.5f*thd[ICc(0,j,i)]    : 0.5f*(thd[ICc(k-1,j,i)]+thd[cc]);
    float thz1 = (k+1==NZ) ? 0.5f*thd[ICc(NZ-1,j,i)] : 0.5f*(thd[cc]+thd[ICc(k+1,j,i)]);
    float s3 = -(Om1*thz1 - Om0*thz0)*rdz;
    To[cc] = Tb[cc] + c*(s1+s2+s3);

    // ---- R_Mu ----
    float rmu = -(Us[IU(k,j,i+1)]-Us[IU(k,j,i)])*rdx
                -(Vs[IV(k,j+1,i)]-Vs[IV(k,j,i)])*rdy
                -(Om1-Om0)*rdz;
    Mo[cc] = Mb[cc] + c*rmu;

    if (k < NZ-1) {
      // ---- R_W ----
      float Uz0 = 0.5f*(Us[IU(k,j,i )]+Us[IU(k+1,j,i )]);
      float Uz1 = 0.5f*(Us[IU(k,j,i+1)]+Us[IU(k+1,j,i+1)]);
      float wx0 = 0.5f*(wd[ICc(k,j,im1)]+wd[cc]);
      float wx1 = 0.5f*(wd[cc]+wd[ICc(k,j,ip1)]);
      float q1 = -(Uz1*wx1 - Uz0*wx0)*rdx;
      float Vz0 = 0.5f*(Vs[IV(k,j ,i)]+Vs[IV(k+1,j ,i)]);
      float Vz1 = 0.5f*(Vs[IV(k,j+1,i)]+Vs[IV(k+1,j+1,i)]);
      float wy0 = 0.5f*(wd[ICc(k,jm1,i)]+wd[cc]);
      float wy1 = 0.5f*(wd[cc]+wd[ICc(k,jp1,i)]);
      float q2 = -(Vz1*wy1 - Vz0*wy0)*rdy;
      float Omz0 = (k==0)      ? 0.5f*Omd[ICc(0,j,i)]    : 0.5f*(Omd[ICc(k-1,j,i)]+Omd[cc]);
      float wz0  = (k==0)      ? 0.5f*wd[ICc(0,j,i)]     : 0.5f*(wd[ICc(k-1,j,i)]+wd[cc]);
      float Omz1 = (k+1==NZ-1) ? 0.5f*Omd[ICc(NZ-2,j,i)] : 0.5f*(Omd[cc]+Omd[ICc(k+1,j,i)]);
      float wz1  = (k+1==NZ-1) ? 0.5f*wd[ICc(NZ-2,j,i)]  : 0.5f*(wd[cc]+wd[ICc(k+1,j,i)]);
      float q3 = -(Omz1*wz1 - Omz0*wz0)*rdz;
      float pw = g*((pd[ICc(k+1,j,i)]-pd[cc])*rdz - 0.5f*(Ms[cc]+Ms[ICc(k+1,j,i)]));
      Wo[cc] = Wb[cc] + c*(q1+q2+q3+pw);

      // ---- R_Phi ----
      float ux0 = 0.5f*(ud[IU(k  ,j,i)]+ud[IU(k  ,j,i+1)]);
      float ux1 = 0.5f*(ud[IU(k+1,j,i)]+ud[IU(k+1,j,i+1)]);
      float uzx = 0.5f*(ux0+ux1);
      float dPhx = 0.5f*(Ps[ICc(k,j,ip1)]-Ps[ICc(k,j,im1)])*rdx;
      float vy0 = 0.5f*(vd[IV(k  ,j,i)]+vd[IV(k  ,j+1,i)]);
      float vy1 = 0.5f*(vd[IV(k+1,j,i)]+vd[IV(k+1,j+1,i)]);
      float vzy = 0.5f*(vy0+vy1);
      float dPhy = 0.5f*(Ps[ICc(k,jp1,i)]-Ps[ICc(k,jm1,i)])*rdy;
      float Phz0 = (k==0)      ? 0.5f*Ps[ICc(0,j,i)]    : 0.5f*(Ps[ICc(k-1,j,i)]+Ps[cc]);
      float Phz1 = (k+1==NZ-1) ? 0.5f*Ps[ICc(NZ-2,j,i)] : 0.5f*(Ps[cc]+Ps[ICc(k+1,j,i)]);
      float p3 = -Omd[cc]*(Phz1-Phz0)*rdz;
      Po[cc] = Pb[cc] + c*(-uzx*dPhx - vzy*dPhy + p3 + g*wd[cc]);
    }
  }
}

extern "C" void kernel_launch(void* const* d_in, const int* in_sizes, int n_in,
                              void* d_out, int out_size, void* d_ws, size_t ws_size,
                              hipStream_t stream)
{
  const float* U = (const float*)d_in[0];
  const float* V = (const float*)d_in[1];
  const float* W = (const float*)d_in[2];
  const float* T = (const float*)d_in[3];
  const float* M = (const float*)d_in[4];
  const float* P = (const float*)d_in[5];
  const float* dxp  = (const float*)d_in[12];
  const float* dyp  = (const float*)d_in[13];
  const float* dzp  = (const float*)d_in[14];
  const float* dtp  = (const float*)d_in[15];
  const float* PREFp= (const float*)d_in[16];
  const float* Rdp  = (const float*)d_in[17];
  const float* gp   = (const float*)d_in[18];

  float* ws = (float*)d_ws;
  float* ud  = ws;        float* vd  = ud +NUT;  float* wd  = vd +NVT;
  float* thd = wd +NWT;   float* ald = thd+NCT;  float* pd  = ald+NCT;
  float* Omd = pd +NCT;
  float* S   = Omd+NWT;
  float* SU=S; float* SV=SU+NUT; float* SW=SV+NVT; float* ST=SW+NWT; float* SM=ST+NCT; float* SP=SM+NCT;

  float* o = (float*)d_out;
  float* OU=o; float* OV=OU+NUT; float* OW=OV+NVT; float* OT=OW+NWT; float* OM=OT+NCT; float* OP=OM+NCT;

  dim3 rb(256,1,1), rg((NUX*NUX+255)/256, NZ, 1);

  auto stage = [&](const float* sU,const float* sV,const float* sW,
                   const float* sT,const float* sM,const float* sP,
                   float* oU,float* oV,float* oW,float* oT,float* oM,float* oP,
                   float cmul){
    hipLaunchKernelGGL(diag_col, dim3((NYX+255)/256), dim3(256), 0, stream,
                       sW,sT,sM,sP, wd,thd,ald,pd,Omd, dzp,PREFp,Rdp,gp);
    hipLaunchKernelGGL(diag_uv, dim3((NUT+NVT+255)/256), dim3(256), 0, stream,
                       sU,sV,sM, ud,vd);
    hipLaunchKernelGGL(rhs_update, rg, rb, 0, stream,
                       sU,sV,sW,sT,sM,sP, ud,vd,wd,thd,ald,pd,Omd,
                       U,V,W,T,M,P, oU,oV,oW,oT,oM,oP,
                       dxp,dyp,dzp,dtp,gp, cmul);
  };

  stage(U,V,W,T,M,P,          OU,OV,OW,OT,OM,OP, 1.f/3.f);
  stage(OU,OV,OW,OT,OM,OP,    SU,SV,SW,ST,SM,SP, 0.5f   );
  stage(SU,SV,SW,ST,SM,SP,    OU,OV,OW,OT,OM,OP, 1.f    );
}

// Round 3
// 435.155 us; speedup vs baseline: 1.4486x; 1.4486x over previous
//
#include <hip/hip_runtime.h>
#include <math.h>

#define NZ 40
#define NY 256
#define NX 256
#define NUX 257                 // Nx+1
#define NYX (NY*NX)             // 65536
#define KU (NY*NUX)             // per-k stride of U
#define KV ((NY+1)*NX)          // per-k stride of V
#define NUT (NZ*KU)
#define NVT (NZ*KV)
#define NCT (NZ*NYX)
#define NWT ((NZ-1)*NYX)

__device__ __forceinline__ int ICc(int k,int j,int i){ return (k*NY+j)*NX+i; }
__device__ __forceinline__ int IU (int k,int j,int i){ return (k*NY+j)*NUX+i; }
__device__ __forceinline__ int IV (int k,int j,int i){ return (k*(NY+1)+j)*NX+i; }

// ---------------- fused diagnostics: u, v, w, theta, alpha, p, Omega ----------------
// grid (257, NZ), block 256.  j=blockIdx.x, k=blockIdx.y, i=threadIdx.x
__global__ __launch_bounds__(256) void diag_all(
    const float* __restrict__ Us, const float* __restrict__ Vs, const float* __restrict__ Ws,
    const float* __restrict__ Ts, const float* __restrict__ Ms, const float* __restrict__ Ps,
    float* __restrict__ ud, float* __restrict__ vd, float* __restrict__ wd,
    float* __restrict__ thd, float* __restrict__ ald, float* __restrict__ pd,
    float* __restrict__ Omd,
    const float* __restrict__ dzp, const float* __restrict__ PREFp,
    const float* __restrict__ Rdp, const float* __restrict__ gp)
{
  const int i = threadIdx.x;     // 0..255
  const int j = blockIdx.x;      // 0..256
  const int k = blockIdx.y;      // 0..NZ-1
  const float rdz = 1.f/(*dzp);
  const float PREF = *PREFp, Rd = *Rdp, g = *gp;
  const float invP = 1.f/PREF;

  const int jj  = j & 255;
  const int jm1 = (j+255) & 255;

  // v = V / bar_y(pad_y(Mu)) : all j in 0..256
  {
    float mjm = Ms[ICc(k,jm1,i)];
    float mjj = Ms[ICc(k,jj,i)];
    int o = IV(k,j,i);
    vd[o] = Vs[o] / (0.5f*(mjm+mjj));
  }

  if (j < NY) {
    const int b = (k*NY+j)*NX;
    // u = U / bar_x(pad_x(Mu))
    float mi  = Ms[b+i];
    float mim = Ms[b+((i+255)&255)];
    ud[IU(k,j,i)] = Us[IU(k,j,i)] / (0.5f*(mim+mi));
    if (i == 255) {   // edge column i=256 on the u-grid
      float m0 = Ms[b+0], m255 = Ms[b+255];
      ud[IU(k,j,256)] = Us[IU(k,j,256)] / (0.5f*(m255+m0));
    }

    // center diagnostics
    const int c = b + i;
    float mu   = mi;
    float phim = (k>0)      ? Ps[c-NYX] : 0.f;
    float phik = (k<NZ-1)   ? Ps[c]     : 0.f;
    float al   = -((phik-phim)*rdz)/mu;
    float th   = Ts[c]/mu;
    float pp   = PREF*powf(Rd*th*invP/al, 1.4f);
    ald[c]=al; thd[c]=th; pd[c]=pp;

    if (k < NZ-1) {
      float mup  = Ms[c+NYX];
      float phip = (k+1<NZ-1) ? Ps[c+NYX] : 0.f;
      float alp  = -((phip-phik)*rdz)/mup;
      float muz = 0.5f*(mu+mup), alz = 0.5f*(al+alp);
      float Wv = Ws[c];
      wd[c]  = Wv/muz;
      Omd[c] = -Wv*g/(muz*alz);
    }
  }
}

// ---------------- R_U helper (used for i=tid and the i=256 edge) ----------------
__device__ __forceinline__ float ru_val(int k,int j,int i,int iW,int iE,int ii,int im1,
    const float* __restrict__ Us, const float* __restrict__ Vs,
    const float* __restrict__ Ms, const float* __restrict__ Ps,
    const float* __restrict__ ud, const float* __restrict__ ald,
    const float* __restrict__ pd, const float* __restrict__ Omd,
    float rdx, float rdy, float rdz)
{
  const int jm1 = (j+255)&255;
  const int jpm = (j+1)&255;
  const int bU  = k*KU + j*NUX;

  float Uim = Us[bU+iW], Ui0 = Us[bU+i], Uip = Us[bU+iE];
  float uim = ud[bU+iW], ui0 = ud[bU+i], uip = ud[bU+iE];
  float t1 = -(0.25f*(Ui0+Uip)*(ui0+uip) - 0.25f*(Uim+Ui0)*(uim+ui0))*rdx;

  float Vx0 = 0.5f*(Vs[IV(k,j  ,im1)] + Vs[IV(k,j  ,ii)]);
  float uy0 = 0.5f*(ud[IU(k,jm1,i)]   + ud[IU(k,j  ,i)]);
  float Vx1 = 0.5f*(Vs[IV(k,j+1,im1)] + Vs[IV(k,j+1,ii)]);
  float uy1 = 0.5f*(ud[IU(k,j  ,i)]   + ud[IU(k,jpm,i)]);
  float t2 = -(Vx1*uy1 - Vx0*uy0)*rdy;

  float Omx0 = (k==0)   ? 0.f : 0.5f*(Omd[ICc(k-1,j,im1)]+Omd[ICc(k-1,j,ii)]);
  float uz0  = (k==0)   ? 0.5f*ud[IU(0,j,i)] : 0.5f*(ud[IU(k-1,j,i)]+ud[IU(k,j,i)]);
  float Omx1 = (k+1==NZ)? 0.f : 0.5f*(Omd[ICc(k,j,im1)]+Omd[ICc(k,j,ii)]);
  float uz1  = (k+1==NZ)? 0.5f*ud[IU(NZ-1,j,i)] : 0.5f*(ud[IU(k,j,i)]+ud[IU(k+1,j,i)]);
  float t3 = -(Omx1*uz1 - Omx0*uz0)*rdz;

  float Mux = 0.5f*(Ms[ICc(k,j,im1)]+Ms[ICc(k,j,ii)]);
  float alx = 0.5f*(ald[ICc(k,j,im1)]+ald[ICc(k,j,ii)]);
  float pt1 = -Mux*alx*(pd[ICc(k,j,ii)]-pd[ICc(k,j,im1)])*rdx;

  auto pzf = [&](int m, int x)->float {
    if (m==0)  return 0.5f*pd[ICc(0,j,x)];
    if (m==NZ) return 0.5f*pd[ICc(NZ-1,j,x)];
    return 0.5f*(pd[ICc(m-1,j,x)]+pd[ICc(m,j,x)]);
  };
  float A = (0.5f*(pzf(k+1,im1)+pzf(k+1,ii)) - 0.5f*(pzf(k,im1)+pzf(k,ii)))*rdz;
  auto Phzf = [&](int x)->float {
    if (k==0)    return 0.5f*Ps[ICc(0,j,x)];
    if (k==NZ-1) return 0.5f*Ps[ICc(NZ-2,j,x)];
    return 0.5f*(Ps[ICc(k-1,j,x)]+Ps[ICc(k,j,x)]);
  };
  float B = (Phzf(ii)-Phzf(im1))*rdx;
  return t1+t2+t3+pt1 + (-A*B);
}

// ---------------- fused RHS + stage update ----------------
// grid (257, NZ), block 256.  out = base + c*R(state)
__global__ __launch_bounds__(256,4) void rhs_update(
    const float* __restrict__ Us, const float* __restrict__ Vs, const float* __restrict__ Ws,
    const float* __restrict__ Ts, const float* __restrict__ Ms, const float* __restrict__ Ps,
    const float* __restrict__ ud, const float* __restrict__ vd, const float* __restrict__ wd,
    const float* __restrict__ thd, const float* __restrict__ ald, const float* __restrict__ pd,
    const float* __restrict__ Omd,
    const float* __restrict__ Ub, const float* __restrict__ Vb, const float* __restrict__ Wb,
    const float* __restrict__ Tb, const float* __restrict__ Mb, const float* __restrict__ Pb,
    float* __restrict__ Uo, float* __restrict__ Vo, float* __restrict__ Wo,
    float* __restrict__ To, float* __restrict__ Mo, float* __restrict__ Po,
    const float* __restrict__ dxp, const float* __restrict__ dyp, const float* __restrict__ dzp,
    const float* __restrict__ dtp, const float* __restrict__ gp, float cmul)
{
  const int i = threadIdx.x;     // 0..255
  const int j = blockIdx.x;      // 0..256
  const int k = blockIdx.y;
  const float rdx = 1.f/(*dxp), rdy = 1.f/(*dyp), rdz = 1.f/(*dzp);
  const float g = *gp;
  const float c = (*dtp)*cmul;

  const int jj  = j & 255;
  const int jm1 = (j+255) & 255;
  const int im1 = (i+255) & 255;
  const int ip1 = (i+1) & 255;

  // ================= R_U : j<NY =================
  if (j < NY) {
    const int iW = i ? (i-1) : 256;
    float rU = ru_val(k,j,i, iW, i+1, i, im1,
                      Us,Vs,Ms,Ps, ud,ald,pd,Omd, rdx,rdy,rdz);
    const int o = IU(k,j,i);
    Uo[o] = Ub[o] + c*rU;
    if (i == 255) {   // U edge column i=256
      float rUe = ru_val(k,j,256, 255, 0, 0, 255,
                         Us,Vs,Ms,Ps, ud,ald,pd,Omd, rdx,rdy,rdz);
      const int oe = IU(k,j,256);
      Uo[oe] = Ub[oe] + c*rUe;
    }
  }

  // ================= R_V : all j in 0..256 =================
  {
    const int jN = (j==0)   ? 256 : j-1;   // (j-1) mod 257 on V-grid
    const int jS = (j==256) ? 0   : j+1;
    float Vjm = Vs[IV(k,jN,i)], Vj0 = Vs[IV(k,j,i)], Vjp = Vs[IV(k,jS,i)];
    float vjm = vd[IV(k,jN,i)], vj0 = vd[IV(k,j,i)], vjp = vd[IV(k,jS,i)];
    float t2 = -(0.25f*(Vj0+Vjp)*(vj0+vjp) - 0.25f*(Vjm+Vj0)*(vjm+vj0))*rdy;

    float Uy0 = 0.5f*(Us[IU(k,jm1,i  )] + Us[IU(k,jj,i  )]);
    float vx0 = 0.5f*(vd[IV(k,j,im1)] + vd[IV(k,j,i)]);
    float Uy1 = 0.5f*(Us[IU(k,jm1,i+1)] + Us[IU(k,jj,i+1)]);
    float vx1 = 0.5f*(vd[IV(k,j,i)] + vd[IV(k,j,ip1)]);
    float t1 = -(Uy1*vx1 - Uy0*vx0)*rdx;

    float Omy0 = (k==0)   ? 0.f : 0.5f*(Omd[ICc(k-1,jm1,i)]+Omd[ICc(k-1,jj,i)]);
    float vz0  = (k==0)   ? 0.5f*vd[IV(0,j,i)] : 0.5f*(vd[IV(k-1,j,i)]+vd[IV(k,j,i)]);
    float Omy1 = (k+1==NZ)? 0.f : 0.5f*(Omd[ICc(k,jm1,i)]+Omd[ICc(k,jj,i)]);
    float vz1  = (k+1==NZ)? 0.5f*vd[IV(NZ-1,j,i)] : 0.5f*(vd[IV(k,j,i)]+vd[IV(k+1,j,i)]);
    float t3 = -(Omy1*vz1 - Omy0*vz0)*rdz;

    float Muy = 0.5f*(Ms[ICc(k,jm1,i)]+Ms[ICc(k,jj,i)]);
    float aly = 0.5f*(ald[ICc(k,jm1,i)]+ald[ICc(k,jj,i)]);
    float pt1 = -Muy*aly*(pd[ICc(k,jj,i)]-pd[ICc(k,jm1,i)])*rdy;

    auto pzfy = [&](int m, int y)->float {
      if (m==0)  return 0.5f*pd[ICc(0,y,i)];
      if (m==NZ) return 0.5f*pd[ICc(NZ-1,y,i)];
      return 0.5f*(pd[ICc(m-1,y,i)]+pd[ICc(m,y,i)]);
    };
    float A = (0.5f*(pzfy(k+1,jm1)+pzfy(k+1,jj)) - 0.5f*(pzfy(k,jm1)+pzfy(k,jj)))*rdz;
    auto Phzfy = [&](int y)->float {
      if (k==0)    return 0.5f*Ps[ICc(0,y,i)];
      if (k==NZ-1) return 0.5f*Ps[ICc(NZ-2,y,i)];
      return 0.5f*(Ps[ICc(k-1,y,i)]+Ps[ICc(k,y,i)]);
    };
    float B = (Phzfy(jj)-Phzfy(jm1))*rdy;
    float pt2 = -A*B;

    const int o = IV(k,j,i);
    Vo[o] = Vb[o] + c*(t1+t2+t3+pt1+pt2);
  }

  // ================= center fields : j<NY =================
  if (j < NY) {
    const int cc = ICc(k,j,i);
    const int jp1 = (j+1)&255;

    // ---- R_Theta ----
    float thx0 = 0.5f*(thd[ICc(k,j,im1)]+thd[cc]);
    float thx1 = 0.5f*(thd[cc]+thd[ICc(k,j,ip1)]);
    float s1 = -(Us[IU(k,j,i+1)]*thx1 - Us[IU(k,j,i)]*thx0)*rdx;
    float thy0 = 0.5f*(thd[ICc(k,jm1,i)]+thd[cc]);
    float thy1 = 0.5f*(thd[cc]+thd[ICc(k,jp1,i)]);
    float s2 = -(Vs[IV(k,j+1,i)]*thy1 - Vs[IV(k,j,i)]*thy0)*rdy;
    float Om0 = (k==0)    ? 0.f : Omd[ICc(k-1,j,i)];
    float Om1 = (k+1==NZ) ? 0.f : Omd[cc];
    float thz0 = (k==0)    ? 0.5f*thd[ICc(0,j,i)]    : 0.5f*(thd[ICc(k-1,j,i)]+thd[cc]);
    float thz1 = (k+1==NZ) ? 0.5f*thd[ICc(NZ-1,j,i)] : 0.5f*(thd[cc]+thd[ICc(k+1,j,i)]);
    float s3 = -(Om1*thz1 - Om0*thz0)*rdz;
    To[cc] = Tb[cc] + c*(s1+s2+s3);

    // ---- R_Mu ----
    float rmu = -(Us[IU(k,j,i+1)]-Us[IU(k,j,i)])*rdx
                -(Vs[IV(k,j+1,i)]-Vs[IV(k,j,i)])*rdy
                -(Om1-Om0)*rdz;
    Mo[cc] = Mb[cc] + c*rmu;

    if (k < NZ-1) {
      // ---- R_W ----
      float Uz0 = 0.5f*(Us[IU(k,j,i  )]+Us[IU(k+1,j,i  )]);
      float Uz1 = 0.5f*(Us[IU(k,j,i+1)]+Us[IU(k+1,j,i+1)]);
      float wx0 = 0.5f*(wd[ICc(k,j,im1)]+wd[cc]);
      float wx1 = 0.5f*(wd[cc]+wd[ICc(k,j,ip1)]);
      float q1 = -(Uz1*wx1 - Uz0*wx0)*rdx;
      float Vz0 = 0.5f*(Vs[IV(k,j  ,i)]+Vs[IV(k+1,j  ,i)]);
      float Vz1 = 0.5f*(Vs[IV(k,j+1,i)]+Vs[IV(k+1,j+1,i)]);
      float wy0 = 0.5f*(wd[ICc(k,jm1,i)]+wd[cc]);
      float wy1 = 0.5f*(wd[cc]+wd[ICc(k,jp1,i)]);
      float q2 = -(Vz1*wy1 - Vz0*wy0)*rdy;
      float Omz0 = (k==0)      ? 0.5f*Omd[ICc(0,j,i)]    : 0.5f*(Omd[ICc(k-1,j,i)]+Omd[cc]);
      float wz0  = (k==0)      ? 0.5f*wd[ICc(0,j,i)]     : 0.5f*(wd[ICc(k-1,j,i)]+wd[cc]);
      float Omz1 = (k+1==NZ-1) ? 0.5f*Omd[ICc(NZ-2,j,i)] : 0.5f*(Omd[cc]+Omd[ICc(k+1,j,i)]);
      float wz1  = (k+1==NZ-1) ? 0.5f*wd[ICc(NZ-2,j,i)]  : 0.5f*(wd[cc]+wd[ICc(k+1,j,i)]);
      float q3 = -(Omz1*wz1 - Omz0*wz0)*rdz;
      float pw = g*((pd[ICc(k+1,j,i)]-pd[cc])*rdz - 0.5f*(Ms[cc]+Ms[ICc(k+1,j,i)]));
      Wo[cc] = Wb[cc] + c*(q1+q2+q3+pw);

      // ---- R_Phi ----
      float ux0 = 0.5f*(ud[IU(k  ,j,i)]+ud[IU(k  ,j,i+1)]);
      float ux1 = 0.5f*(ud[IU(k+1,j,i)]+ud[IU(k+1,j,i+1)]);
      float uzx = 0.5f*(ux0+ux1);
      float dPhx = 0.5f*(Ps[ICc(k,j,ip1)]-Ps[ICc(k,j,im1)])*rdx;
      float vy0 = 0.5f*(vd[IV(k  ,j,i)]+vd[IV(k  ,j+1,i)]);
      float vy1 = 0.5f*(vd[IV(k+1,j,i)]+vd[IV(k+1,j+1,i)]);
      float vzy = 0.5f*(vy0+vy1);
      float dPhy = 0.5f*(Ps[ICc(k,jp1,i)]-Ps[ICc(k,jm1,i)])*rdy;
      float Phz0 = (k==0)      ? 0.5f*Ps[ICc(0,j,i)]    : 0.5f*(Ps[ICc(k-1,j,i)]+Ps[cc]);
      float Phz1 = (k+1==NZ-1) ? 0.5f*Ps[ICc(NZ-2,j,i)] : 0.5f*(Ps[cc]+Ps[ICc(k+1,j,i)]);
      float p3 = -Omd[cc]*(Phz1-Phz0)*rdz;
      Po[cc] = Pb[cc] + c*(-uzx*dPhx - vzy*dPhy + p3 + g*wd[cc]);
    }
  }
}

extern "C" void kernel_launch(void* const* d_in, const int* in_sizes, int n_in,
                              void* d_out, int out_size, void* d_ws, size_t ws_size,
                              hipStream_t stream)
{
  const float* U = (const float*)d_in[0];
  const float* V = (const float*)d_in[1];
  const float* W = (const float*)d_in[2];
  const float* T = (const float*)d_in[3];
  const float* M = (const float*)d_in[4];
  const float* P = (const float*)d_in[5];
  const float* dxp  = (const float*)d_in[12];
  const float* dyp  = (const float*)d_in[13];
  const float* dzp  = (const float*)d_in[14];
  const float* dtp  = (const float*)d_in[15];
  const float* PREFp= (const float*)d_in[16];
  const float* Rdp  = (const float*)d_in[17];
  const float* gp   = (const float*)d_in[18];

  float* ws = (float*)d_ws;
  float* ud  = ws;        float* vd  = ud +NUT;  float* wd  = vd +NVT;
  float* thd = wd +NWT;   float* ald = thd+NCT;  float* pd  = ald+NCT;
  float* Omd = pd +NCT;
  float* S   = Omd+NWT;
  float* SU=S; float* SV=SU+NUT; float* SW=SV+NVT; float* ST=SW+NWT; float* SM=ST+NCT; float* SP=SM+NCT;

  float* o = (float*)d_out;
  float* OU=o; float* OV=OU+NUT; float* OW=OV+NVT; float* OT=OW+NWT; float* OM=OT+NCT; float* OP=OM+NCT;

  dim3 blk(256,1,1), grd(NUX, NZ, 1);

  auto stage = [&](const float* sU,const float* sV,const float* sW,
                   const float* sT,const float* sM,const float* sP,
                   float* oU,float* oV,float* oW,float* oT,float* oM,float* oP,
                   float cmul){
    hipLaunchKernelGGL(diag_all, grd, blk, 0, stream,
                       sU,sV,sW,sT,sM,sP, ud,vd,wd,thd,ald,pd,Omd, dzp,PREFp,Rdp,gp);
    hipLaunchKernelGGL(rhs_update, grd, blk, 0, stream,
                       sU,sV,sW,sT,sM,sP, ud,vd,wd,thd,ald,pd,Omd,
                       U,V,W,T,M,P, oU,oV,oW,oT,oM,oP,
                       dxp,dyp,dzp,dtp,gp, cmul);
  };

  stage(U,V,W,T,M,P,          OU,OV,OW,OT,OM,OP, 1.f/3.f);
  stage(OU,OV,OW,OT,OM,OP,    SU,SV,SW,ST,SM,SP, 0.5f   );
  stage(SU,SV,SW,ST,SM,SP,    OU,OV,OW,OT,OM,OP, 1.f    );
}

// Round 4
// 395.021 us; speedup vs baseline: 1.5958x; 1.1016x over previous
//
#include <hip/hip_runtime.h>
#include <math.h>

#define NZ 40
#define NY 256
#define NX 256
#define NUX 257                 // Nx+1
#define NYX (NY*NX)             // 65536
#define KU (NY*NUX)             // per-k stride of U
#define KV ((NY+1)*NX)          // per-k stride of V
#define NUT (NZ*KU)
#define NVT (NZ*KV)
#define NCT (NZ*NYX)
#define NWT ((NZ-1)*NYX)
#define NBLK (NUX*NZ)           // 10280 = 8*1285

__device__ __forceinline__ int ICc(int k,int j,int i){ return (k*NY+j)*NX+i; }
__device__ __forceinline__ int IU (int k,int j,int i){ return (k*NY+j)*NUX+i; }
__device__ __forceinline__ int IV (int k,int j,int i){ return (k*(NY+1)+j)*NX+i; }

// ---- on-the-fly diagnostics (cheap: 1 divide + cached loads) ----
__device__ __forceinline__ float u_at(const float* __restrict__ Us, const float* __restrict__ Ms,
                                      int k,int j,int i){    // i in [0,256]
  const int ii = i & 255, im = (i+255) & 255;
  const int b = (k*NY+j)*NX;
  return Us[(k*NY+j)*NUX+i] / (0.5f*(Ms[b+im]+Ms[b+ii]));
}
__device__ __forceinline__ float v_at(const float* __restrict__ Vs, const float* __restrict__ Ms,
                                      int k,int j,int i){    // j in [0,256]
  const int jj = j & 255, jm = (j+255) & 255;
  return Vs[(k*(NY+1)+j)*NX+i] / (0.5f*(Ms[(k*NY+jm)*NX+i]+Ms[(k*NY+jj)*NX+i]));
}
__device__ __forceinline__ float w_at(const float* __restrict__ Ws, const float* __restrict__ Ms,
                                      int k,int j,int i){    // k in [0,NZ-2]
  const int c = (k*NY+j)*NX+i;
  return Ws[c] / (0.5f*(Ms[c]+Ms[c+NYX]));
}
__device__ __forceinline__ float th_at(const float* __restrict__ Ts, const float* __restrict__ Ms,
                                       int k,int j,int i){
  const int c = (k*NY+j)*NX+i;
  return Ts[c]/Ms[c];
}
__device__ __forceinline__ float al_at(const float* __restrict__ Ps, const float* __restrict__ Ms,
                                       int k,int j,int i, float rdz){
  const int c = (k*NY+j)*NX+i;
  float phim = (k>0)    ? Ps[c-NYX] : 0.f;
  float phik = (k<NZ-1) ? Ps[c]     : 0.f;
  return -((phik-phim)*rdz)/Ms[c];
}

// ---------------- small diag: p (powf) and Omega ----------------
// grid (256, NZ), block 256
__global__ __launch_bounds__(256) void diag_pOm(
    const float* __restrict__ Ws, const float* __restrict__ Ts,
    const float* __restrict__ Ms, const float* __restrict__ Ps,
    float* __restrict__ pd, float* __restrict__ Omd,
    const float* __restrict__ dzp, const float* __restrict__ PREFp,
    const float* __restrict__ Rdp, const float* __restrict__ gp)
{
  const int i = threadIdx.x, j = blockIdx.x, k = blockIdx.y;
  const float rdz = 1.f/(*dzp);
  const float PREF = *PREFp, Rd = *Rdp, g = *gp;
  const float invP = 1.f/PREF;
  const int c = ICc(k,j,i);
  float mu   = Ms[c];
  float phim = (k>0)    ? Ps[c-NYX] : 0.f;
  float phik = (k<NZ-1) ? Ps[c]     : 0.f;
  float al   = -((phik-phim)*rdz)/mu;
  float th   = Ts[c]/mu;
  pd[c] = PREF*powf(Rd*th*invP/al, 1.4f);
  if (k < NZ-1) {
    float mup  = Ms[c+NYX];
    float phip = (k+1<NZ-1) ? Ps[c+NYX] : 0.f;
    float alp  = -((phip-phik)*rdz)/mup;
    Omd[c] = -Ws[c]*g/((0.5f*(mu+mup))*(0.5f*(al+alp)));
  }
}

// ---------------- R_U helper ----------------
__device__ __forceinline__ float ru_val(int k,int j,int i,int iW,int iE,
    const float* __restrict__ Us, const float* __restrict__ Vs,
    const float* __restrict__ Ms, const float* __restrict__ Ps,
    const float* __restrict__ pd, const float* __restrict__ Omd,
    float rdx, float rdy, float rdz)
{
  const int ii  = i & 255;
  const int im1 = (i+255) & 255;
  const int jm1 = (j+255) & 255;
  const int jpm = (j+1) & 255;
  const int bU  = k*KU + j*NUX;

  float ui0 = u_at(Us,Ms,k,j,i);
  float uim = u_at(Us,Ms,k,j,iW);
  float uip = u_at(Us,Ms,k,j,iE);
  float Uim = Us[bU+iW], Ui0 = Us[bU+i], Uip = Us[bU+iE];
  float t1 = -(0.25f*(Ui0+Uip)*(ui0+uip) - 0.25f*(Uim+Ui0)*(uim+ui0))*rdx;

  float Vx0 = 0.5f*(Vs[IV(k,j  ,im1)] + Vs[IV(k,j  ,ii)]);
  float uy0 = 0.5f*(u_at(Us,Ms,k,jm1,i) + ui0);
  float Vx1 = 0.5f*(Vs[IV(k,j+1,im1)] + Vs[IV(k,j+1,ii)]);
  float uy1 = 0.5f*(ui0 + u_at(Us,Ms,k,jpm,i));
  float t2 = -(Vx1*uy1 - Vx0*uy0)*rdy;

  float Omx0 = (k==0)   ? 0.f : 0.5f*(Omd[ICc(k-1,j,im1)]+Omd[ICc(k-1,j,ii)]);
  float uz0  = (k==0)   ? 0.5f*ui0 : 0.5f*(u_at(Us,Ms,k-1,j,i)+ui0);
  float Omx1 = (k+1==NZ)? 0.f : 0.5f*(Omd[ICc(k,j,im1)]+Omd[ICc(k,j,ii)]);
  float uz1  = (k+1==NZ)? 0.5f*ui0 : 0.5f*(ui0+u_at(Us,Ms,k+1,j,i));
  float t3 = -(Omx1*uz1 - Omx0*uz0)*rdz;

  float Mux = 0.5f*(Ms[ICc(k,j,im1)]+Ms[ICc(k,j,ii)]);
  float alx = 0.5f*(al_at(Ps,Ms,k,j,im1,rdz)+al_at(Ps,Ms,k,j,ii,rdz));
  float pt1 = -Mux*alx*(pd[ICc(k,j,ii)]-pd[ICc(k,j,im1)])*rdx;

  auto pzf = [&](int m, int x)->float {
    if (m==0)  return 0.5f*pd[ICc(0,j,x)];
    if (m==NZ) return 0.5f*pd[ICc(NZ-1,j,x)];
    return 0.5f*(pd[ICc(m-1,j,x)]+pd[ICc(m,j,x)]);
  };
  float A = (0.5f*(pzf(k+1,im1)+pzf(k+1,ii)) - 0.5f*(pzf(k,im1)+pzf(k,ii)))*rdz;
  auto Phzf = [&](int x)->float {
    if (k==0)    return 0.5f*Ps[ICc(0,j,x)];
    if (k==NZ-1) return 0.5f*Ps[ICc(NZ-2,j,x)];
    return 0.5f*(Ps[ICc(k-1,j,x)]+Ps[ICc(k,j,x)]);
  };
  float B = (Phzf(ii)-Phzf(im1))*rdx;
  return t1+t2+t3+pt1 + (-A*B);
}

// ---------------- fused RHS + stage update ----------------
// 1D grid NBLK with XCD swizzle; block 256.  out = base + c*R(state)
__global__ __launch_bounds__(256,4) void rhs_update(
    const float* __restrict__ Us, const float* __restrict__ Vs, const float* __restrict__ Ws,
    const float* __restrict__ Ts, const float* __restrict__ Ms, const float* __restrict__ Ps,
    const float* __restrict__ pd, const float* __restrict__ Omd,
    const float* __restrict__ Ub, const float* __restrict__ Vb, const float* __restrict__ Wb,
    const float* __restrict__ Tb, const float* __restrict__ Mb, const float* __restrict__ Pb,
    float* __restrict__ Uo, float* __restrict__ Vo, float* __restrict__ Wo,
    float* __restrict__ To, float* __restrict__ Mo, float* __restrict__ Po,
    const float* __restrict__ dxp, const float* __restrict__ dyp, const float* __restrict__ dzp,
    const float* __restrict__ dtp, const float* __restrict__ gp, float cmul)
{
  // bijective XCD swizzle: NBLK = 8 * 1285
  const int bid = blockIdx.x;
  const int nb  = (bid & 7)*(NBLK/8) + (bid >> 3);
  const int j   = nb / NZ;       // 0..256
  const int k   = nb - NZ*j;     // 0..NZ-1
  const int i   = threadIdx.x;   // 0..255

  const float rdx = 1.f/(*dxp), rdy = 1.f/(*dyp), rdz = 1.f/(*dzp);
  const float g = *gp;
  const float c = (*dtp)*cmul;

  const int jj  = j & 255;
  const int jm1 = (j+255) & 255;
  const int im1 = (i+255) & 255;
  const int ip1 = (i+1) & 255;

  // ================= R_U : j<NY =================
  if (j < NY) {
    const int iW = i ? (i-1) : 256;
    float rU = ru_val(k,j,i, iW, i+1, Us,Vs,Ms,Ps, pd,Omd, rdx,rdy,rdz);
    const int o = IU(k,j,i);
    Uo[o] = Ub[o] + c*rU;
    if (i == 255) {   // U edge column i=256 (wrap: iW=255, iE=0)
      float rUe = ru_val(k,j,256, 255, 0, Us,Vs,Ms,Ps, pd,Omd, rdx,rdy,rdz);
      const int oe = IU(k,j,256);
      Uo[oe] = Ub[oe] + c*rUe;
    }
  }

  // ================= R_V : all j in 0..256 =================
  {
    const int jN = (j==0)   ? 256 : j-1;   // (j-1) mod 257 on V-grid
    const int jS = (j==256) ? 0   : j+1;
    float vj0 = v_at(Vs,Ms,k,j,i);
    float vjm = v_at(Vs,Ms,k,jN,i);
    float vjp = v_at(Vs,Ms,k,jS,i);
    float Vjm = Vs[IV(k,jN,i)], Vj0 = Vs[IV(k,j,i)], Vjp = Vs[IV(k,jS,i)];
    float t2 = -(0.25f*(Vj0+Vjp)*(vj0+vjp) - 0.25f*(Vjm+Vj0)*(vjm+vj0))*rdy;

    float Uy0 = 0.5f*(Us[IU(k,jm1,i  )] + Us[IU(k,jj,i  )]);
    float vx0 = 0.5f*(v_at(Vs,Ms,k,j,im1) + vj0);
    float Uy1 = 0.5f*(Us[IU(k,jm1,i+1)] + Us[IU(k,jj,i+1)]);
    float vx1 = 0.5f*(vj0 + v_at(Vs,Ms,k,j,ip1));
    float t1 = -(Uy1*vx1 - Uy0*vx0)*rdx;

    float Omy0 = (k==0)   ? 0.f : 0.5f*(Omd[ICc(k-1,jm1,i)]+Omd[ICc(k-1,jj,i)]);
    float vz0  = (k==0)   ? 0.5f*vj0 : 0.5f*(v_at(Vs,Ms,k-1,j,i)+vj0);
    float Omy1 = (k+1==NZ)? 0.f : 0.5f*(Omd[ICc(k,jm1,i)]+Omd[ICc(k,jj,i)]);
    float vz1  = (k+1==NZ)? 0.5f*vj0 : 0.5f*(vj0+v_at(Vs,Ms,k+1,j,i));
    float t3 = -(Omy1*vz1 - Omy0*vz0)*rdz;

    float Muy = 0.5f*(Ms[ICc(k,jm1,i)]+Ms[ICc(k,jj,i)]);
    float aly = 0.5f*(al_at(Ps,Ms,k,jm1,i,rdz)+al_at(Ps,Ms,k,jj,i,rdz));
    float pt1 = -Muy*aly*(pd[ICc(k,jj,i)]-pd[ICc(k,jm1,i)])*rdy;

    auto pzfy = [&](int m, int y)->float {
      if (m==0)  return 0.5f*pd[ICc(0,y,i)];
      if (m==NZ) return 0.5f*pd[ICc(NZ-1,y,i)];
      return 0.5f*(pd[ICc(m-1,y,i)]+pd[ICc(m,y,i)]);
    };
    float A = (0.5f*(pzfy(k+1,jm1)+pzfy(k+1,jj)) - 0.5f*(pzfy(k,jm1)+pzfy(k,jj)))*rdz;
    auto Phzfy = [&](int y)->float {
      if (k==0)    return 0.5f*Ps[ICc(0,y,i)];
      if (k==NZ-1) return 0.5f*Ps[ICc(NZ-2,y,i)];
      return 0.5f*(Ps[ICc(k-1,y,i)]+Ps[ICc(k,y,i)]);
    };
    float B = (Phzfy(jj)-Phzfy(jm1))*rdy;
    float pt2 = -A*B;

    const int o = IV(k,j,i);
    Vo[o] = Vb[o] + c*(t1+t2+t3+pt1+pt2);
  }

  // ================= center fields : j<NY =================
  if (j < NY) {
    const int cc = ICc(k,j,i);
    const int jp1 = (j+1)&255;

    // ---- R_Theta ----
    float th0 = th_at(Ts,Ms,k,j,i);
    float thx0 = 0.5f*(th_at(Ts,Ms,k,j,im1)+th0);
    float thx1 = 0.5f*(th0+th_at(Ts,Ms,k,j,ip1));
    float s1 = -(Us[IU(k,j,i+1)]*thx1 - Us[IU(k,j,i)]*thx0)*rdx;
    float thy0 = 0.5f*(th_at(Ts,Ms,k,jm1,i)+th0);
    float thy1 = 0.5f*(th0+th_at(Ts,Ms,k,jp1,i));
    float s2 = -(Vs[IV(k,j+1,i)]*thy1 - Vs[IV(k,j,i)]*thy0)*rdy;
    float Om0 = (k==0)    ? 0.f : Omd[ICc(k-1,j,i)];
    float Om1 = (k+1==NZ) ? 0.f : Omd[cc];
    float thz0 = (k==0)    ? 0.5f*th0 : 0.5f*(th_at(Ts,Ms,k-1,j,i)+th0);
    float thz1 = (k+1==NZ) ? 0.5f*th0 : 0.5f*(th0+th_at(Ts,Ms,k+1,j,i));
    float s3 = -(Om1*thz1 - Om0*thz0)*rdz;
    To[cc] = Tb[cc] + c*(s1+s2+s3);

    // ---- R_Mu ----
    float rmu = -(Us[IU(k,j,i+1)]-Us[IU(k,j,i)])*rdx
                -(Vs[IV(k,j+1,i)]-Vs[IV(k,j,i)])*rdy
                -(Om1-Om0)*rdz;
    Mo[cc] = Mb[cc] + c*rmu;

    if (k < NZ-1) {
      float w0 = w_at(Ws,Ms,k,j,i);
      // ---- R_W ----
      float Uz0 = 0.5f*(Us[IU(k,j,i  )]+Us[IU(k+1,j,i  )]);
      float Uz1 = 0.5f*(Us[IU(k,j,i+1)]+Us[IU(k+1,j,i+1)]);
      float wx0 = 0.5f*(w_at(Ws,Ms,k,j,im1)+w0);
      float wx1 = 0.5f*(w0+w_at(Ws,Ms,k,j,ip1));
      float q1 = -(Uz1*wx1 - Uz0*wx0)*rdx;
      float Vz0 = 0.5f*(Vs[IV(k,j  ,i)]+Vs[IV(k+1,j  ,i)]);
      float Vz1 = 0.5f*(Vs[IV(k,j+1,i)]+Vs[IV(k+1,j+1,i)]);
      float wy0 = 0.5f*(w_at(Ws,Ms,k,jm1,i)+w0);
      float wy1 = 0.5f*(w0+w_at(Ws,Ms,k,jp1,i));
      float q2 = -(Vz1*wy1 - Vz0*wy0)*rdy;
      float Omz0 = (k==0)      ? 0.5f*Omd[ICc(0,j,i)]    : 0.5f*(Omd[ICc(k-1,j,i)]+Omd[cc]);
      float wz0  = (k==0)      ? 0.5f*w0 : 0.5f*(w_at(Ws,Ms,k-1,j,i)+w0);
      float Omz1 = (k+1==NZ-1) ? 0.5f*Omd[ICc(NZ-2,j,i)] : 0.5f*(Omd[cc]+Omd[ICc(k+1,j,i)]);
      float wz1  = (k+1==NZ-1) ? 0.5f*w0 : 0.5f*(w0+w_at(Ws,Ms,k+1,j,i));
      float q3 = -(Omz1*wz1 - Omz0*wz0)*rdz;
      float pw = g*((pd[ICc(k+1,j,i)]-pd[cc])*rdz - 0.5f*(Ms[cc]+Ms[ICc(k+1,j,i)]));
      Wo[cc] = Wb[cc] + c*(q1+q2+q3+pw);

      // ---- R_Phi ----
      float ux0 = 0.5f*(u_at(Us,Ms,k  ,j,i)+u_at(Us,Ms,k  ,j,i+1));
      float ux1 = 0.5f*(u_at(Us,Ms,k+1,j,i)+u_at(Us,Ms,k+1,j,i+1));
      float uzx = 0.5f*(ux0+ux1);
      float dPhx = 0.5f*(Ps[ICc(k,j,ip1)]-Ps[ICc(k,j,im1)])*rdx;
      float vy0 = 0.5f*(v_at(Vs,Ms,k  ,j,i)+v_at(Vs,Ms,k  ,j+1,i));
      float vy1 = 0.5f*(v_at(Vs,Ms,k+1,j,i)+v_at(Vs,Ms,k+1,j+1,i));
      float vzy = 0.5f*(vy0+vy1);
      float dPhy = 0.5f*(Ps[ICc(k,jp1,i)]-Ps[ICc(k,jm1,i)])*rdy;
      float Phz0 = (k==0)      ? 0.5f*Ps[ICc(0,j,i)]    : 0.5f*(Ps[ICc(k-1,j,i)]+Ps[cc]);
      float Phz1 = (k+1==NZ-1) ? 0.5f*Ps[ICc(NZ-2,j,i)] : 0.5f*(Ps[cc]+Ps[ICc(k+1,j,i)]);
      float p3 = -Omd[cc]*(Phz1-Phz0)*rdz;
      Po[cc] = Pb[cc] + c*(-uzx*dPhx - vzy*dPhy + p3 + g*w0);
    }
  }
}

extern "C" void kernel_launch(void* const* d_in, const int* in_sizes, int n_in,
                              void* d_out, int out_size, void* d_ws, size_t ws_size,
                              hipStream_t stream)
{
  const float* U = (const float*)d_in[0];
  const float* V = (const float*)d_in[1];
  const float* W = (const float*)d_in[2];
  const float* T = (const float*)d_in[3];
  const float* M = (const float*)d_in[4];
  const float* P = (const float*)d_in[5];
  const float* dxp  = (const float*)d_in[12];
  const float* dyp  = (const float*)d_in[13];
  const float* dzp  = (const float*)d_in[14];
  const float* dtp  = (const float*)d_in[15];
  const float* PREFp= (const float*)d_in[16];
  const float* Rdp  = (const float*)d_in[17];
  const float* gp   = (const float*)d_in[18];

  float* ws = (float*)d_ws;
  float* pd  = ws;
  float* Omd = pd + NCT;
  float* S   = Omd + NWT;
  float* SU=S; float* SV=SU+NUT; float* SW=SV+NVT; float* ST=SW+NWT; float* SM=ST+NCT; float* SP=SM+NCT;

  float* o = (float*)d_out;
  float* OU=o; float* OV=OU+NUT; float* OW=OV+NVT; float* OT=OW+NWT; float* OM=OT+NCT; float* OP=OM+NCT;

  dim3 blk(256,1,1);
  dim3 dgrd(NY, NZ, 1);          // diag: center fields only
  dim3 rgrd(NBLK, 1, 1);         // rhs: swizzled 1D

  auto stage = [&](const float* sU,const float* sV,const float* sW,
                   const float* sT,const float* sM,const float* sP,
                   float* oU,float* oV,float* oW,float* oT,float* oM,float* oP,
                   float cmul){
    hipLaunchKernelGGL(diag_pOm, dgrd, blk, 0, stream,
                       sW,sT,sM,sP, pd,Omd, dzp,PREFp,Rdp,gp);
    hipLaunchKernelGGL(rhs_update, rgrd, blk, 0, stream,
                       sU,sV,sW,sT,sM,sP, pd,Omd,
                       U,V,W,T,M,P, oU,oV,oW,oT,oM,oP,
                       dxp,dyp,dzp,dtp,gp, cmul);
  };

  stage(U,V,W,T,M,P,          OU,OV,OW,OT,OM,OP, 1.f/3.f);
  stage(OU,OV,OW,OT,OM,OP,    SU,SV,SW,ST,SM,SP, 0.5f   );
  stage(SU,SV,SW,ST,SM,SP,    OU,OV,OW,OT,OM,OP, 1.f    );
}

// Round 5
// 319.837 us; speedup vs baseline: 1.9709x; 1.2351x over previous
//
#include <hip/hip_runtime.h>
#include <math.h>

#define NZ 40
#define NY 256
#define NX 256
#define NUX 257                 // Nx+1
#define NYX (NY*NX)             // 65536
#define KU (NY*NUX)             // per-k stride of U
#define KV ((NY+1)*NX)          // per-k stride of V
#define NUT (NZ*KU)
#define NVT (NZ*KV)
#define NCT (NZ*NYX)
#define NWT ((NZ-1)*NYX)
#define NBLK (NUX*NZ)           // 10280 = 8*1285

__device__ __forceinline__ int ICc(int k,int j,int i){ return (k*NY+j)*NX+i; }
__device__ __forceinline__ int IU (int k,int j,int i){ return (k*NY+j)*NUX+i; }
__device__ __forceinline__ int IV (int k,int j,int i){ return (k*(NY+1)+j)*NX+i; }

// fast divide: v_rcp_f32 (trans pipe, ~1e-5 rel err) + mul.  Tolerance is 0.645,
// current margin 1.2e-4 -> safe.
__device__ __forceinline__ float fdiv(float a, float b){
  return a * __builtin_amdgcn_rcpf(b);
}

// ---- on-the-fly diagnostics (1 rcp + few VALU ops each) ----
__device__ __forceinline__ float u_at(const float* __restrict__ Us, const float* __restrict__ Ms,
                                      int k,int j,int i){    // i in [0,256]
  const int ii = i & 255, im = (i+255) & 255;
  const int b = (k*NY+j)*NX;
  return fdiv(Us[(k*NY+j)*NUX+i], 0.5f*(Ms[b+im]+Ms[b+ii]));
}
__device__ __forceinline__ float v_at(const float* __restrict__ Vs, const float* __restrict__ Ms,
                                      int k,int j,int i){    // j in [0,256]
  const int jj = j & 255, jm = (j+255) & 255;
  return fdiv(Vs[(k*(NY+1)+j)*NX+i], 0.5f*(Ms[(k*NY+jm)*NX+i]+Ms[(k*NY+jj)*NX+i]));
}
__device__ __forceinline__ float w_at(const float* __restrict__ Ws, const float* __restrict__ Ms,
                                      int k,int j,int i){    // k in [0,NZ-2]
  const int c = (k*NY+j)*NX+i;
  return fdiv(Ws[c], 0.5f*(Ms[c]+Ms[c+NYX]));
}
__device__ __forceinline__ float th_at(const float* __restrict__ Ts, const float* __restrict__ Ms,
                                       int k,int j,int i){
  const int c = (k*NY+j)*NX+i;
  return fdiv(Ts[c], Ms[c]);
}

// ---------------- small diag: p (powf), Omega, alpha ----------------
// grid (256, NZ), block 256
__global__ __launch_bounds__(256) void diag_pOm(
    const float* __restrict__ Ws, const float* __restrict__ Ts,
    const float* __restrict__ Ms, const float* __restrict__ Ps,
    float* __restrict__ pd, float* __restrict__ Omd, float* __restrict__ ald,
    const float* __restrict__ dzp, const float* __restrict__ PREFp,
    const float* __restrict__ Rdp, const float* __restrict__ gp)
{
  const int i = threadIdx.x, j = blockIdx.x, k = blockIdx.y;
  const float rdz = 1.f/(*dzp);
  const float PREF = *PREFp, Rd = *Rdp, g = *gp;
  const float invP = 1.f/PREF;
  const int c = ICc(k,j,i);
  float mu   = Ms[c];
  float phim = (k>0)    ? Ps[c-NYX] : 0.f;
  float phik = (k<NZ-1) ? Ps[c]     : 0.f;
  float al   = -((phik-phim)*rdz)/mu;
  float th   = Ts[c]/mu;
  pd[c]  = PREF*powf(Rd*th*invP/al, 1.4f);
  ald[c] = al;
  if (k < NZ-1) {
    float mup  = Ms[c+NYX];
    float phip = (k+1<NZ-1) ? Ps[c+NYX] : 0.f;
    float alp  = -((phip-phik)*rdz)/mup;
    Omd[c] = -Ws[c]*g/((0.5f*(mu+mup))*(0.5f*(al+alp)));
  }
}

// ---------------- R_U helper ----------------
__device__ __forceinline__ float ru_val(int k,int j,int i,int iW,int iE,
    const float* __restrict__ Us, const float* __restrict__ Vs,
    const float* __restrict__ Ms, const float* __restrict__ Ps,
    const float* __restrict__ pd, const float* __restrict__ Omd,
    const float* __restrict__ ald,
    float rdx, float rdy, float rdz)
{
  const int ii  = i & 255;
  const int im1 = (i+255) & 255;
  const int jm1 = (j+255) & 255;
  const int jpm = (j+1) & 255;
  const int bU  = k*KU + j*NUX;

  float ui0 = u_at(Us,Ms,k,j,i);
  float uim = u_at(Us,Ms,k,j,iW);
  float uip = u_at(Us,Ms,k,j,iE);
  float Uim = Us[bU+iW], Ui0 = Us[bU+i], Uip = Us[bU+iE];
  float t1 = -(0.25f*(Ui0+Uip)*(ui0+uip) - 0.25f*(Uim+Ui0)*(uim+ui0))*rdx;

  float Vx0 = 0.5f*(Vs[IV(k,j  ,im1)] + Vs[IV(k,j  ,ii)]);
  float uy0 = 0.5f*(u_at(Us,Ms,k,jm1,i) + ui0);
  float Vx1 = 0.5f*(Vs[IV(k,j+1,im1)] + Vs[IV(k,j+1,ii)]);
  float uy1 = 0.5f*(ui0 + u_at(Us,Ms,k,jpm,i));
  float t2 = -(Vx1*uy1 - Vx0*uy0)*rdy;

  float Omx0 = (k==0)   ? 0.f : 0.5f*(Omd[ICc(k-1,j,im1)]+Omd[ICc(k-1,j,ii)]);
  float uz0  = (k==0)   ? 0.5f*ui0 : 0.5f*(u_at(Us,Ms,k-1,j,i)+ui0);
  float Omx1 = (k+1==NZ)? 0.f : 0.5f*(Omd[ICc(k,j,im1)]+Omd[ICc(k,j,ii)]);
  float uz1  = (k+1==NZ)? 0.5f*ui0 : 0.5f*(ui0+u_at(Us,Ms,k+1,j,i));
  float t3 = -(Omx1*uz1 - Omx0*uz0)*rdz;

  float Mux = 0.5f*(Ms[ICc(k,j,im1)]+Ms[ICc(k,j,ii)]);
  float alx = 0.5f*(ald[ICc(k,j,im1)]+ald[ICc(k,j,ii)]);
  float pt1 = -Mux*alx*(pd[ICc(k,j,ii)]-pd[ICc(k,j,im1)])*rdx;

  auto pzf = [&](int m, int x)->float {
    if (m==0)  return 0.5f*pd[ICc(0,j,x)];
    if (m==NZ) return 0.5f*pd[ICc(NZ-1,j,x)];
    return 0.5f*(pd[ICc(m-1,j,x)]+pd[ICc(m,j,x)]);
  };
  float A = (0.5f*(pzf(k+1,im1)+pzf(k+1,ii)) - 0.5f*(pzf(k,im1)+pzf(k,ii)))*rdz;
  auto Phzf = [&](int x)->float {
    if (k==0)    return 0.5f*Ps[ICc(0,j,x)];
    if (k==NZ-1) return 0.5f*Ps[ICc(NZ-2,j,x)];
    return 0.5f*(Ps[ICc(k-1,j,x)]+Ps[ICc(k,j,x)]);
  };
  float B = (Phzf(ii)-Phzf(im1))*rdx;
  return t1+t2+t3+pt1 + (-A*B);
}

// ---------------- fused RHS + stage update ----------------
// 1D grid NBLK with XCD swizzle; block 256.  out = base + c*R(state)
__global__ __launch_bounds__(256,8) void rhs_update(
    const float* __restrict__ Us, const float* __restrict__ Vs, const float* __restrict__ Ws,
    const float* __restrict__ Ts, const float* __restrict__ Ms, const float* __restrict__ Ps,
    const float* __restrict__ pd, const float* __restrict__ Omd, const float* __restrict__ ald,
    const float* __restrict__ Ub, const float* __restrict__ Vb, const float* __restrict__ Wb,
    const float* __restrict__ Tb, const float* __restrict__ Mb, const float* __restrict__ Pb,
    float* __restrict__ Uo, float* __restrict__ Vo, float* __restrict__ Wo,
    float* __restrict__ To, float* __restrict__ Mo, float* __restrict__ Po,
    const float* __restrict__ dxp, const float* __restrict__ dyp, const float* __restrict__ dzp,
    const float* __restrict__ dtp, const float* __restrict__ gp, float cmul)
{
  // bijective XCD swizzle: NBLK = 8 * 1285
  const int bid = blockIdx.x;
  const int nb  = (bid & 7)*(NBLK/8) + (bid >> 3);
  const int j   = nb / NZ;       // 0..256
  const int k   = nb - NZ*j;     // 0..NZ-1
  const int i   = threadIdx.x;   // 0..255

  const float rdx = 1.f/(*dxp), rdy = 1.f/(*dyp), rdz = 1.f/(*dzp);
  const float g = *gp;
  const float c = (*dtp)*cmul;

  const int jj  = j & 255;
  const int jm1 = (j+255) & 255;
  const int im1 = (i+255) & 255;
  const int ip1 = (i+1) & 255;

  // ================= R_U : j<NY =================
  if (j < NY) {
    const int iW = i ? (i-1) : 256;
    float rU = ru_val(k,j,i, iW, i+1, Us,Vs,Ms,Ps, pd,Omd,ald, rdx,rdy,rdz);
    const int o = IU(k,j,i);
    Uo[o] = Ub[o] + c*rU;
    if (i == 255) {   // U edge column i=256 (wrap: iW=255, iE=0)
      float rUe = ru_val(k,j,256, 255, 0, Us,Vs,Ms,Ps, pd,Omd,ald, rdx,rdy,rdz);
      const int oe = IU(k,j,256);
      Uo[oe] = Ub[oe] + c*rUe;
    }
  }

  // ================= R_V : all j in 0..256 =================
  {
    const int jN = (j==0)   ? 256 : j-1;   // (j-1) mod 257 on V-grid
    const int jS = (j==256) ? 0   : j+1;
    float vj0 = v_at(Vs,Ms,k,j,i);
    float vjm = v_at(Vs,Ms,k,jN,i);
    float vjp = v_at(Vs,Ms,k,jS,i);
    float Vjm = Vs[IV(k,jN,i)], Vj0 = Vs[IV(k,j,i)], Vjp = Vs[IV(k,jS,i)];
    float t2 = -(0.25f*(Vj0+Vjp)*(vj0+vjp) - 0.25f*(Vjm+Vj0)*(vjm+vj0))*rdy;

    float Uy0 = 0.5f*(Us[IU(k,jm1,i  )] + Us[IU(k,jj,i  )]);
    float vx0 = 0.5f*(v_at(Vs,Ms,k,j,im1) + vj0);
    float Uy1 = 0.5f*(Us[IU(k,jm1,i+1)] + Us[IU(k,jj,i+1)]);
    float vx1 = 0.5f*(vj0 + v_at(Vs,Ms,k,j,ip1));
    float t1 = -(Uy1*vx1 - Uy0*vx0)*rdx;

    float Omy0 = (k==0)   ? 0.f : 0.5f*(Omd[ICc(k-1,jm1,i)]+Omd[ICc(k-1,jj,i)]);
    float vz0  = (k==0)   ? 0.5f*vj0 : 0.5f*(v_at(Vs,Ms,k-1,j,i)+vj0);
    float Omy1 = (k+1==NZ)? 0.f : 0.5f*(Omd[ICc(k,jm1,i)]+Omd[ICc(k,jj,i)]);
    float vz1  = (k+1==NZ)? 0.5f*vj0 : 0.5f*(vj0+v_at(Vs,Ms,k+1,j,i));
    float t3 = -(Omy1*vz1 - Omy0*vz0)*rdz;

    float Muy = 0.5f*(Ms[ICc(k,jm1,i)]+Ms[ICc(k,jj,i)]);
    float aly = 0.5f*(ald[ICc(k,jm1,i)]+ald[ICc(k,jj,i)]);
    float pt1 = -Muy*aly*(pd[ICc(k,jj,i)]-pd[ICc(k,jm1,i)])*rdy;

    auto pzfy = [&](int m, int y)->float {
      if (m==0)  return 0.5f*pd[ICc(0,y,i)];
      if (m==NZ) return 0.5f*pd[ICc(NZ-1,y,i)];
      return 0.5f*(pd[ICc(m-1,y,i)]+pd[ICc(m,y,i)]);
    };
    float A = (0.5f*(pzfy(k+1,jm1)+pzfy(k+1,jj)) - 0.5f*(pzfy(k,jm1)+pzfy(k,jj)))*rdz;
    auto Phzfy = [&](int y)->float {
      if (k==0)    return 0.5f*Ps[ICc(0,y,i)];
      if (k==NZ-1) return 0.5f*Ps[ICc(NZ-2,y,i)];
      return 0.5f*(Ps[ICc(k-1,y,i)]+Ps[ICc(k,y,i)]);
    };
    float B = (Phzfy(jj)-Phzfy(jm1))*rdy;
    float pt2 = -A*B;

    const int o = IV(k,j,i);
    Vo[o] = Vb[o] + c*(t1+t2+t3+pt1+pt2);
  }

  // ================= center fields : j<NY =================
  if (j < NY) {
    const int cc = ICc(k,j,i);
    const int jp1 = (j+1)&255;

    // ---- R_Theta ----
    float th0 = th_at(Ts,Ms,k,j,i);
    float thx0 = 0.5f*(th_at(Ts,Ms,k,j,im1)+th0);
    float thx1 = 0.5f*(th0+th_at(Ts,Ms,k,j,ip1));
    float s1 = -(Us[IU(k,j,i+1)]*thx1 - Us[IU(k,j,i)]*thx0)*rdx;
    float thy0 = 0.5f*(th_at(Ts,Ms,k,jm1,i)+th0);
    float thy1 = 0.5f*(th0+th_at(Ts,Ms,k,jp1,i));
    float s2 = -(Vs[IV(k,j+1,i)]*thy1 - Vs[IV(k,j,i)]*thy0)*rdy;
    float Om0 = (k==0)    ? 0.f : Omd[ICc(k-1,j,i)];
    float Om1 = (k+1==NZ) ? 0.f : Omd[cc];
    float thz0 = (k==0)    ? 0.5f*th0 : 0.5f*(th_at(Ts,Ms,k-1,j,i)+th0);
    float thz1 = (k+1==NZ) ? 0.5f*th0 : 0.5f*(th0+th_at(Ts,Ms,k+1,j,i));
    float s3 = -(Om1*thz1 - Om0*thz0)*rdz;
    To[cc] = Tb[cc] + c*(s1+s2+s3);

    // ---- R_Mu ----
    float rmu = -(Us[IU(k,j,i+1)]-Us[IU(k,j,i)])*rdx
                -(Vs[IV(k,j+1,i)]-Vs[IV(k,j,i)])*rdy
                -(Om1-Om0)*rdz;
    Mo[cc] = Mb[cc] + c*rmu;

    if (k < NZ-1) {
      float w0 = w_at(Ws,Ms,k,j,i);
      // ---- R_W ----
      float Uz0 = 0.5f*(Us[IU(k,j,i  )]+Us[IU(k+1,j,i  )]);
      float Uz1 = 0.5f*(Us[IU(k,j,i+1)]+Us[IU(k+1,j,i+1)]);
      float wx0 = 0.5f*(w_at(Ws,Ms,k,j,im1)+w0);
      float wx1 = 0.5f*(w0+w_at(Ws,Ms,k,j,ip1));
      float q1 = -(Uz1*wx1 - Uz0*wx0)*rdx;
      float Vz0 = 0.5f*(Vs[IV(k,j  ,i)]+Vs[IV(k+1,j  ,i)]);
      float Vz1 = 0.5f*(Vs[IV(k,j+1,i)]+Vs[IV(k+1,j+1,i)]);
      float wy0 = 0.5f*(w_at(Ws,Ms,k,jm1,i)+w0);
      float wy1 = 0.5f*(w0+w_at(Ws,Ms,k,jp1,i));
      float q2 = -(Vz1*wy1 - Vz0*wy0)*rdy;
      float Omz0 = (k==0)      ? 0.5f*Omd[ICc(0,j,i)]    : 0.5f*(Omd[ICc(k-1,j,i)]+Omd[cc]);
      float wz0  = (k==0)      ? 0.5f*w0 : 0.5f*(w_at(Ws,Ms,k-1,j,i)+w0);
      float Omz1 = (k+1==NZ-1) ? 0.5f*Omd[ICc(NZ-2,j,i)] : 0.5f*(Omd[cc]+Omd[ICc(k+1,j,i)]);
      float wz1  = (k+1==NZ-1) ? 0.5f*w0 : 0.5f*(w0+w_at(Ws,Ms,k+1,j,i));
      float q3 = -(Omz1*wz1 - Omz0*wz0)*rdz;
      float pw = g*((pd[ICc(k+1,j,i)]-pd[cc])*rdz - 0.5f*(Ms[cc]+Ms[ICc(k+1,j,i)]));
      Wo[cc] = Wb[cc] + c*(q1+q2+q3+pw);

      // ---- R_Phi ----
      float ux0 = 0.5f*(u_at(Us,Ms,k  ,j,i)+u_at(Us,Ms,k  ,j,i+1));
      float ux1 = 0.5f*(u_at(Us,Ms,k+1,j,i)+u_at(Us,Ms,k+1,j,i+1));
      float uzx = 0.5f*(ux0+ux1);
      float dPhx = 0.5f*(Ps[ICc(k,j,ip1)]-Ps[ICc(k,j,im1)])*rdx;
      float vy0 = 0.5f*(v_at(Vs,Ms,k  ,j,i)+v_at(Vs,Ms,k  ,j+1,i));
      float vy1 = 0.5f*(v_at(Vs,Ms,k+1,j,i)+v_at(Vs,Ms,k+1,j+1,i));
      float vzy = 0.5f*(vy0+vy1);
      float dPhy = 0.5f*(Ps[ICc(k,jp1,i)]-Ps[ICc(k,jm1,i)])*rdy;
      float Phz0 = (k==0)      ? 0.5f*Ps[ICc(0,j,i)]    : 0.5f*(Ps[ICc(k-1,j,i)]+Ps[cc]);
      float Phz1 = (k+1==NZ-1) ? 0.5f*Ps[ICc(NZ-2,j,i)] : 0.5f*(Ps[cc]+Ps[ICc(k+1,j,i)]);
      float p3 = -Omd[cc]*(Phz1-Phz0)*rdz;
      Po[cc] = Pb[cc] + c*(-uzx*dPhx - vzy*dPhy + p3 + g*w0);
    }
  }
}

extern "C" void kernel_launch(void* const* d_in, const int* in_sizes, int n_in,
                              void* d_out, int out_size, void* d_ws, size_t ws_size,
                              hipStream_t stream)
{
  const float* U = (const float*)d_in[0];
  const float* V = (const float*)d_in[1];
  const float* W = (const float*)d_in[2];
  const float* T = (const float*)d_in[3];
  const float* M = (const float*)d_in[4];
  const float* P = (const float*)d_in[5];
  const float* dxp  = (const float*)d_in[12];
  const float* dyp  = (const float*)d_in[13];
  const float* dzp  = (const float*)d_in[14];
  const float* dtp  = (const float*)d_in[15];
  const float* PREFp= (const float*)d_in[16];
  const float* Rdp  = (const float*)d_in[17];
  const float* gp   = (const float*)d_in[18];

  float* ws = (float*)d_ws;
  float* pd  = ws;
  float* Omd = pd  + NCT;
  float* ald = Omd + NWT;
  float* S   = ald + NCT;
  float* SU=S; float* SV=SU+NUT; float* SW=SV+NVT; float* ST=SW+NWT; float* SM=ST+NCT; float* SP=SM+NCT;

  float* o = (float*)d_out;
  float* OU=o; float* OV=OU+NUT; float* OW=OV+NVT; float* OT=OW+NWT; float* OM=OT+NCT; float* OP=OM+NCT;

  dim3 blk(256,1,1);
  dim3 dgrd(NY, NZ, 1);          // diag: center fields only
  dim3 rgrd(NBLK, 1, 1);         // rhs: swizzled 1D

  auto stage = [&](const float* sU,const float* sV,const float* sW,
                   const float* sT,const float* sM,const float* sP,
                   float* oU,float* oV,float* oW,float* oT,float* oM,float* oP,
                   float cmul){
    hipLaunchKernelGGL(diag_pOm, dgrd, blk, 0, stream,
                       sW,sT,sM,sP, pd,Omd,ald, dzp,PREFp,Rdp,gp);
    hipLaunchKernelGGL(rhs_update, rgrd, blk, 0, stream,
                       sU,sV,sW,sT,sM,sP, pd,Omd,ald,
                       U,V,W,T,M,P, oU,oV,oW,oT,oM,oP,
                       dxp,dyp,dzp,dtp,gp, cmul);
  };

  stage(U,V,W,T,M,P,          OU,OV,OW,OT,OM,OP, 1.f/3.f);
  stage(OU,OV,OW,OT,OM,OP,    SU,SV,SW,ST,SM,SP, 0.5f   );
  stage(SU,SV,SW,ST,SM,SP,    OU,OV,OW,OT,OM,OP, 1.f    );
}